// Round 5
// baseline (768.898 us; speedup 1.0000x reference)
//
#include <hip/hip_runtime.h>
#include <hip/hip_bf16.h>
#include <stdint.h>

#define B_ 2
#define T_ 1024
#define C_ 2048
#define H_ 16
#define D_ 128
#define P_ 1024
#define L_ 2048   // P + T
#define M_ 2048   // B*T

typedef unsigned short u16;
typedef __attribute__((ext_vector_type(8))) short short8;   // MFMA A/B frag (8 bf16)
typedef __attribute__((ext_vector_type(4))) float f32x4;    // MFMA C/D frag
typedef __attribute__((ext_vector_type(8))) u16 u16x8;      // 16B LDS vector
typedef __attribute__((ext_vector_type(4))) u16 u16x4;      // 8B LDS vector
typedef __attribute__((ext_vector_type(2))) u16 u16x2;
typedef __attribute__((ext_vector_type(4))) uint32_t u32x4;

__device__ __forceinline__ u16 f2bf(float x) {
    union { float f; uint32_t u; } c; c.f = x;
    uint32_t u = c.u;
    return (u16)((u + 0x7fffu + ((u >> 16) & 1u)) >> 16);   // RNE
}
__device__ __forceinline__ uint32_t pk2(float x, float y) {   // v_cvt_pk_bf16_f32
    union { __hip_bfloat162 h; uint32_t u; } c;
    c.h = __float22bfloat162_rn(float2{x, y});
    return c.u;
}
__device__ __forceinline__ u16x8 cvt8(float4 a, float4 b) {
    union { u32x4 v; u16x8 s; } c;
    c.v = u32x4{pk2(a.x, a.y), pk2(a.z, a.w), pk2(b.x, b.y), pk2(b.z, b.w)};
    return c.s;
}

// ---------------------------------------------------------------------------
__global__ __launch_bounds__(256) void zero_ws_kernel(u16x8* __restrict__ p) {
    p[blockIdx.x * 256 + threadIdx.x] = u16x8{0,0,0,0,0,0,0,0};
}

// ---------------------------------------------------------------------------
// Copy past_k/past_v [B,H,P,D] f32 into k/v cache [B,H,L,D] f32 at l < P.
__global__ __launch_bounds__(256) void copy_past_kernel(
        const float4* __restrict__ pk, const float4* __restrict__ pv,
        float4* __restrict__ kdst, float4* __restrict__ vdst) {
    int i = blockIdx.x * 256 + threadIdx.x;   // float4 idx; total B*H*P*D/4 = 1048576
    int bh = i >> 15;                          // / (P*D/4 = 32768)
    int rest = i & 32767;
    size_t dst = (size_t)bh * (L_ * D_ / 4) + rest;
    kdst[dst] = pk[i];
    vdst[dst] = pv[i];
}

// ---------------------------------------------------------------------------
// Fused QKV NT GEMM, 128x128 tile, 256 threads (4 waves as 2x2, 4x4 accs each).
// A: x f32 [M,K]. Bx: weights f32 [N,K]. grp 0 -> Q (bf16 to Qst [M,C]),
// grp 1 -> K scatter f32, grp 2 -> V scatter f32 into [B,H,L,D] at l=P+t.
__global__ __launch_bounds__(256) void gemm_qkv(
        const float* __restrict__ A,
        const float* __restrict__ Wq, const float* __restrict__ Wk,
        const float* __restrict__ Wv,
        u16* __restrict__ Qst, float* __restrict__ kout, float* __restrict__ vout) {
    __shared__ u16 As[128][40];   // 80B rows (16B-aligned)
    __shared__ u16 Bs[128][40];
    const int tid  = threadIdx.x;
    const int wave = tid >> 6;
    const int lane = tid & 63;
    const int wr = wave >> 1, wc = wave & 1;
    const int grp = blockIdx.x >> 4;
    const int n0 = (blockIdx.x & 15) * 128;
    const int m0 = blockIdx.y * 128;
    const float* Bm = (grp == 0) ? Wq : (grp == 1) ? Wk : Wv;

    f32x4 acc[4][4];
#pragma unroll
    for (int i = 0; i < 4; ++i)
#pragma unroll
        for (int j = 0; j < 4; ++j) acc[i][j] = f32x4{0.f, 0.f, 0.f, 0.f};

    const int srow = tid >> 1;           // 0..127
    const int scol = (tid & 1) * 16;     // 0 or 16
    const float* Ap = A  + (size_t)(m0 + srow) * C_ + scol;
    const float* Bp = Bm + (size_t)(n0 + srow) * C_ + scol;
    const int frow = lane & 15;
    const int fko  = (lane >> 4) * 8;

    for (int kt = 0; kt < C_; kt += 32) {
        float4 a0 = *(const float4*)(Ap + kt);
        float4 a1 = *(const float4*)(Ap + kt + 4);
        float4 a2 = *(const float4*)(Ap + kt + 8);
        float4 a3 = *(const float4*)(Ap + kt + 12);
        float4 b0 = *(const float4*)(Bp + kt);
        float4 b1 = *(const float4*)(Bp + kt + 4);
        float4 b2 = *(const float4*)(Bp + kt + 8);
        float4 b3 = *(const float4*)(Bp + kt + 12);
        __syncthreads();
        *(u16x8*)&As[srow][scol]     = cvt8(a0, a1);
        *(u16x8*)&As[srow][scol + 8] = cvt8(a2, a3);
        *(u16x8*)&Bs[srow][scol]     = cvt8(b0, b1);
        *(u16x8*)&Bs[srow][scol + 8] = cvt8(b2, b3);
        __syncthreads();
        short8 af[4], bf[4];
#pragma unroll
        for (int mi = 0; mi < 4; ++mi)
            af[mi] = *(const short8*)&As[wr * 64 + mi * 16 + frow][fko];
#pragma unroll
        for (int ni = 0; ni < 4; ++ni)
            bf[ni] = *(const short8*)&Bs[wc * 64 + ni * 16 + frow][fko];
#pragma unroll
        for (int mi = 0; mi < 4; ++mi)
#pragma unroll
            for (int ni = 0; ni < 4; ++ni)
                acc[mi][ni] = __builtin_amdgcn_mfma_f32_16x16x32_bf16(
                    af[mi], bf[ni], acc[mi][ni], 0, 0, 0);
    }

    // C/D layout: col = lane&15, row = (lane>>4)*4 + reg  [verified m89/m91]
    const int ccol = lane & 15;
    const int crb  = (lane >> 4) * 4;
    float* sc = (grp == 1) ? kout : vout;
#pragma unroll
    for (int mi = 0; mi < 4; ++mi) {
#pragma unroll
        for (int ni = 0; ni < 4; ++ni) {
            int gc = n0 + wc * 64 + ni * 16 + ccol;
#pragma unroll
            for (int r = 0; r < 4; ++r) {
                int gr = m0 + wr * 64 + mi * 16 + crb + r;
                float v = acc[mi][ni][r];
                if (grp == 0) {
                    Qst[(size_t)gr * C_ + gc] = f2bf(v);
                } else {
                    int b = gr >> 10, t = gr & 1023;   // gr = b*T + t
                    int h = gc >> 7,  d = gc & 127;    // gc = h*D + d
                    sc[(((size_t)(b * H_ + h)) * L_ + P_ + t) * D_ + d] = v;
                }
            }
        }
    }
}

// ---------------------------------------------------------------------------
// Final projection: out[m,n] = sum_k Ost_bf16[m,k] * Wp[n,k] + bp[n], f32 out.
// Same 128x128 structure; A is already bf16.
__global__ __launch_bounds__(256) void gemm_proj(
        const u16* __restrict__ Ab, const float* __restrict__ Bm,
        float* __restrict__ out, const float* __restrict__ bias) {
    __shared__ u16 As[128][40];
    __shared__ u16 Bs[128][40];
    const int tid  = threadIdx.x;
    const int wave = tid >> 6;
    const int lane = tid & 63;
    const int wr = wave >> 1, wc = wave & 1;
    const int n0 = blockIdx.x * 128;
    const int m0 = blockIdx.y * 128;

    f32x4 acc[4][4];
#pragma unroll
    for (int i = 0; i < 4; ++i)
#pragma unroll
        for (int j = 0; j < 4; ++j) acc[i][j] = f32x4{0.f, 0.f, 0.f, 0.f};

    const int srow = tid >> 1;
    const int scol = (tid & 1) * 16;
    const u16*   Ap = Ab + (size_t)(m0 + srow) * C_ + scol;
    const float* Bp = Bm + (size_t)(n0 + srow) * C_ + scol;
    const int frow = lane & 15;
    const int fko  = (lane >> 4) * 8;

    for (int kt = 0; kt < C_; kt += 32) {
        u16x8 av0 = *(const u16x8*)(Ap + kt);
        u16x8 av1 = *(const u16x8*)(Ap + kt + 8);
        float4 b0 = *(const float4*)(Bp + kt);
        float4 b1 = *(const float4*)(Bp + kt + 4);
        float4 b2 = *(const float4*)(Bp + kt + 8);
        float4 b3 = *(const float4*)(Bp + kt + 12);
        __syncthreads();
        *(u16x8*)&As[srow][scol]     = av0;
        *(u16x8*)&As[srow][scol + 8] = av1;
        *(u16x8*)&Bs[srow][scol]     = cvt8(b0, b1);
        *(u16x8*)&Bs[srow][scol + 8] = cvt8(b2, b3);
        __syncthreads();
        short8 af[4], bf[4];
#pragma unroll
        for (int mi = 0; mi < 4; ++mi)
            af[mi] = *(const short8*)&As[wr * 64 + mi * 16 + frow][fko];
#pragma unroll
        for (int ni = 0; ni < 4; ++ni)
            bf[ni] = *(const short8*)&Bs[wc * 64 + ni * 16 + frow][fko];
#pragma unroll
        for (int mi = 0; mi < 4; ++mi)
#pragma unroll
            for (int ni = 0; ni < 4; ++ni)
                acc[mi][ni] = __builtin_amdgcn_mfma_f32_16x16x32_bf16(
                    af[mi], bf[ni], acc[mi][ni], 0, 0, 0);
    }

    const int ccol = lane & 15;
    const int crb  = (lane >> 4) * 4;
#pragma unroll
    for (int mi = 0; mi < 4; ++mi) {
#pragma unroll
        for (int ni = 0; ni < 4; ++ni) {
            int gc = n0 + wc * 64 + ni * 16 + ccol;
            float badd = bias[gc];
#pragma unroll
            for (int r = 0; r < 4; ++r) {
                int gr = m0 + wr * 64 + mi * 16 + crb + r;
                out[(size_t)gr * C_ + gc] = acc[mi][ni][r] + badd;
            }
        }
    }
}

// ---------------------------------------------------------------------------
// MFMA flash attention. One block = (b, h, 64 query rows). K/V chunks of 64.
// Q: bf16 [B,T,C]. Kc/Vc: f32 cache [B,H,L,D]. O: bf16 [B,T,C].
// LDS layouts chosen for bank-conflict freedom:
//   Qs/Ks rows 136 u16 (stride 68 dw, !=0 mod 32)
//   VsT rows 74 u16 (stride 37 dw; scalar transpose writes d=lane-stride-1 ->
//   banks 5*lane mod 32 -> 2 lanes/bank = free [m136])
#define NEG_BIG -30000.f
__global__ __launch_bounds__(256) void attn_kernel(
        const u16* __restrict__ Q, const float* __restrict__ Kc,
        const float* __restrict__ Vc, u16* __restrict__ O) {
    __shared__ u16 Qs[64][136];
    __shared__ u16 Ks[64][136];
    __shared__ u16 VsT[128][74];  // transposed V chunk: VsT[d][key]
    __shared__ u16 Ps[64][72];    // P tile

    const int tid  = threadIdx.x;
    const int wave = tid >> 6;
    const int lane = tid & 63;
    const int qt = blockIdx.x & 15;          // T/64 = 16 q-tiles
    const int h  = (blockIdx.x >> 4) & 15;
    const int b  = blockIdx.x >> 8;
    const int t0 = qt * 64;

    const float* Kb = Kc + ((size_t)(b * H_ + h)) * L_ * D_;
    const float* Vb = Vc + ((size_t)(b * H_ + h)) * L_ * D_;

    // Stage Q tile (64 rows x 128 dims, bf16 source)
    {
        int r  = tid >> 2;
        int d0 = (tid & 3) * 32;
        const u16* src = Q + ((size_t)(b * T_ + t0 + r)) * C_ + h * D_ + d0;
#pragma unroll
        for (int u = 0; u < 4; ++u)
            *(u16x8*)&Qs[r][d0 + u * 8] = *(const u16x8*)(src + u * 8);
    }

    const int frow = lane & 15;
    const int quad = lane >> 4;
    const int fko  = quad * 8;

    f32x4 o_acc[8];
#pragma unroll
    for (int n = 0; n < 8; ++n) o_acc[n] = f32x4{0.f, 0.f, 0.f, 0.f};
    float m_i[4] = {NEG_BIG, NEG_BIG, NEG_BIG, NEG_BIG};
    float l_i[4] = {0.f, 0.f, 0.f, 0.f};
    const float scale = 0.08838834764831845f;   // 1/sqrt(128)

    const int nch = (P_ + t0 + 64) >> 6;

    for (int ch = 0; ch < nch; ++ch) {
        const int j0 = ch * 64;
        __syncthreads();   // prior iter's LDS consumers done (covers Q staging too)
        {   // K chunk row-major (vector), V chunk transposed (scalar, conflict-free)
            const float* kg = Kb + (size_t)j0 * D_;
            const float* vg = Vb + (size_t)j0 * D_;
#pragma unroll
            for (int s = 0; s < 8; ++s) {
                int e = s * 1024 + tid * 4;       // element idx within 64x128
                int kr = e >> 7, kc = e & 127;
                float4 k4 = *(const float4*)(kg + e);
                union { uint32_t w[2]; u16x4 v; } kc4;
                kc4.w[0] = pk2(k4.x, k4.y);
                kc4.w[1] = pk2(k4.z, k4.w);
                *(u16x4*)&Ks[kr][kc] = kc4.v;
            }
#pragma unroll
            for (int s = 0; s < 32; ++s) {
                int e = s * 256 + tid;            // key = e>>7, d = e&127
                VsT[e & 127][e >> 7] = f2bf(vg[e]);
            }
        }
        __syncthreads();

        // S = Q_tile(wave's 16 rows) @ K_chunk^T  -> 4 col-tiles of 16 keys
        f32x4 st[4];
#pragma unroll
        for (int j = 0; j < 4; ++j) st[j] = f32x4{0.f, 0.f, 0.f, 0.f};
#pragma unroll
        for (int kt = 0; kt < 4; ++kt) {
            short8 a = *(const short8*)&Qs[wave * 16 + frow][kt * 32 + fko];
#pragma unroll
            for (int j = 0; j < 4; ++j) {
                short8 bf = *(const short8*)&Ks[j * 16 + frow][kt * 32 + fko];
                st[j] = __builtin_amdgcn_mfma_f32_16x16x32_bf16(a, bf, st[j], 0, 0, 0);
            }
        }

        // Online softmax. Lane holds rows quad*4+r, col frow (+16j).
#pragma unroll
        for (int r = 0; r < 4; ++r) {
            const int t   = t0 + wave * 16 + quad * 4 + r;
            const int lim = P_ + t;      // attend keys j <= lim
            float sv[4];
            float mx = NEG_BIG;
#pragma unroll
            for (int j = 0; j < 4; ++j) {
                int jg = j0 + j * 16 + frow;
                float s = st[j][r] * scale;
                s = (jg <= lim) ? s : NEG_BIG;
                sv[j] = s;
                mx = fmaxf(mx, s);
            }
#pragma unroll
            for (int sft = 1; sft <= 8; sft <<= 1)
                mx = fmaxf(mx, __shfl_xor(mx, sft, 64));
            float m_new = fmaxf(m_i[r], mx);
            float alpha = __expf(fminf(m_i[r] - m_new, 0.f));
            float rs = 0.f;
#pragma unroll
            for (int j = 0; j < 4; ++j) {
                float p = __expf(fminf(sv[j] - m_new, 0.f));
                p = (sv[j] <= NEG_BIG) ? 0.f : p;   // masked -> exactly 0
                sv[j] = p;
                rs += p;
            }
#pragma unroll
            for (int sft = 1; sft <= 8; sft <<= 1)
                rs += __shfl_xor(rs, sft, 64);
            l_i[r] = l_i[r] * alpha + rs;
            m_i[r] = m_new;
#pragma unroll
            for (int n = 0; n < 8; ++n) o_acc[n][r] *= alpha;
#pragma unroll
            for (int j = 0; j < 4; ++j)
                Ps[wave * 16 + quad * 4 + r][j * 16 + frow] = f2bf(sv[j]);
        }
        __syncthreads();   // Ps stores visible before vector reads

        // PV: O(16x128) += P(16x64) @ V_chunk(64x128). B-frags from VsT rows
        // via 4x ds_read_b32 (conflict-free by layout).
#pragma unroll
        for (int kt2 = 0; kt2 < 2; ++kt2) {
            short8 a = *(const short8*)&Ps[wave * 16 + frow][kt2 * 32 + fko];
#pragma unroll
            for (int n = 0; n < 8; ++n) {
                const u16* vrow = &VsT[n * 16 + frow][kt2 * 32 + fko];
                u16x2 p0 = *(const u16x2*)(vrow);
                u16x2 p1 = *(const u16x2*)(vrow + 2);
                u16x2 p2 = *(const u16x2*)(vrow + 4);
                u16x2 p3 = *(const u16x2*)(vrow + 6);
                short8 bf = short8{(short)p0.x, (short)p0.y, (short)p1.x, (short)p1.y,
                                   (short)p2.x, (short)p2.y, (short)p3.x, (short)p3.y};
                o_acc[n] = __builtin_amdgcn_mfma_f32_16x16x32_bf16(a, bf, o_acc[n], 0, 0, 0);
            }
        }
    }

    // Epilogue: O /= l, store bf16 [B,T,C]
#pragma unroll
    for (int r = 0; r < 4; ++r) {
        float rl = 1.f / fmaxf(l_i[r], 1e-30f);
        int t = t0 + wave * 16 + quad * 4 + r;
#pragma unroll
        for (int n = 0; n < 8; ++n) {
            float v = o_acc[n][r] * rl;
            O[((size_t)(b * T_ + t)) * C_ + h * D_ + n * 16 + frow] = f2bf(v);
        }
    }
}

// ---------------------------------------------------------------------------
extern "C" void kernel_launch(void* const* d_in, const int* in_sizes, int n_in,
                              void* d_out, int out_size, void* d_ws, size_t ws_size,
                              hipStream_t stream) {
    const float* x      = (const float*)d_in[0];
    const float* past_k = (const float*)d_in[1];
    const float* past_v = (const float*)d_in[2];
    const float* Wk     = (const float*)d_in[3];
    const float* Wq     = (const float*)d_in[4];
    const float* Wv     = (const float*)d_in[5];
    const float* Wp     = (const float*)d_in[6];
    const float* bp     = (const float*)d_in[7];

    float* out  = (float*)d_out;             // [B,T,C]    4,194,304 f32 (16 MB)
    float* kout = out + 4194304;             // [B,H,L,D]  8,388,608 f32
    float* vout = kout + 8388608;            // [B,H,L,D]  8,388,608 f32

    // Q (bf16, 8 MB) in d_out's out region (dead until final GEMM overwrites
    // it). O (bf16, 8 MB) in ws.
    u16* Qst = (u16*)d_out;
    u16* Ost = (u16*)d_ws;

    zero_ws_kernel<<<2048, 256, 0, stream>>>((u16x8*)Ost);

    copy_past_kernel<<<4096, 256, 0, stream>>>(
        (const float4*)past_k, (const float4*)past_v,
        (float4*)kout, (float4*)vout);

    gemm_qkv<<<dim3(48, 16), 256, 0, stream>>>(x, Wq, Wk, Wv, Qst, kout, vout);

    attn_kernel<<<512, 256, 0, stream>>>(Qst, kout, vout, Ost);

    gemm_proj<<<dim3(16, 16), 256, 0, stream>>>(Ost, Wp, out, bp);
}